// Round 2
// baseline (1153.725 us; speedup 1.0000x reference)
//
#include <hip/hip_runtime.h>

// P2B_XCorr: B=8, F=128, M=256, N=1024, H=64, O=128. All inputs fp32, output fp32.
// (R1 NaN post-mortem: buffers are fp32; reading them as bf16 made ~0.4% of
//  low-halves decode as bf16 NaN. This round: identical structure, fp32 I/O.)
//
// Algebra: bn_i folded to affine (a_i,c_i); a folded into conv weights.
//   h1[h,m,n] = relu(A1[h,m] + u[h]*cos[m,n]),  A1 = a1*(W1[:,1:]@t)+c1, u = a1*W1[:,0]
//   h2 = relu(W2f@h1 + c2), h3 = relu(W3f@h2 + c3), p = max_m h3  (running max, no BxHxMxN tensor)
//   c = relu(Wc1f@p + cc1), out = Wc2@c + bc2

#define BB 8
#define FF 128
#define MM 256
#define NN 1024
#define HH 64
#define OO 128
#define BN_EPS 1e-5f
#define COS_EPS 1e-8f

// workspace layout (float offsets); total 2,251,008 floats = 8.6 MiB
#define WS_U     0
#define WS_C2    64
#define WS_C3    128
#define WS_CC1   192
#define WS_W2F   256          // [g][h] 64x64
#define WS_W3F   4352
#define WS_WC1F  8448
#define WS_A1    12544        // [b][m][h]  8*256*64
#define WS_NT    143616       // [b][m]
#define WS_NS    145664       // [b][n]
#define WS_COS   153856       // [b][n][m]  8*1024*256

__device__ __forceinline__ float dot4(float4 a, float4 b, float acc){
  acc = fmaf(a.x, b.x, acc); acc = fmaf(a.y, b.y, acc);
  acc = fmaf(a.z, b.z, acc); acc = fmaf(a.w, b.w, acc);
  return acc;
}

// ---------------- K0: fold BN params into weights ----------------
__global__ __launch_bounds__(256) void k_fold(
    const float* W1, const float* W2, const float* W3, const float* Wc1,
    const float* g1, const float* b1, const float* m1, const float* v1,
    const float* g2, const float* b2, const float* m2, const float* v2,
    const float* g3, const float* b3, const float* m3, const float* v3,
    const float* gc1,const float* bc1,const float* mc1,const float* vc1,
    float* ws){
  int t = threadIdx.x;
  if (t < 64){
    float a1 = g1[t] / sqrtf(v1[t] + BN_EPS);
    ws[WS_U + t]   = a1 * W1[t*129];                 // W1[:,0] scaled
    float a2 = g2[t] / sqrtf(v2[t] + BN_EPS);
    ws[WS_C2 + t]  = b2[t] - a2*m2[t];
    float a3 = g3[t] / sqrtf(v3[t] + BN_EPS);
    ws[WS_C3 + t]  = b3[t] - a3*m3[t];
    float ac = gc1[t] / sqrtf(vc1[t] + BN_EPS);
    ws[WS_CC1 + t] = bc1[t] - ac*mc1[t];
  }
  for (int i = t; i < 4096; i += 256){
    int g = i >> 6;
    float a2 = g2[g] / sqrtf(v2[g] + BN_EPS);
    ws[WS_W2F + i]  = a2 * W2[i];
    float a3 = g3[g] / sqrtf(v3[g] + BN_EPS);
    ws[WS_W3F + i]  = a3 * W3[i];
    float ac = gc1[g] / sqrtf(vc1[g] + BN_EPS);
    ws[WS_WC1F + i] = ac * Wc1[i];
  }
}

// ---------------- K1a: A1[b][m][h] = a1*(W1[:,1:] @ t) + c1 ----------------
__global__ __launch_bounds__(256) void k_a1(const float* t_, const float* W1,
    const float* g1, const float* b1, const float* m1, const float* v1, float* ws){
  int t = threadIdx.x;
  int h = t & 63;
  int m = blockIdx.x*4 + (t >> 6);
  int b = blockIdx.y;
  float acc = 0.f;
  const float* w = W1 + h*129 + 1;
  const float* tp = t_ + (size_t)b*FF*MM + m;
  for (int f = 0; f < FF; f++) acc = fmaf(w[f], tp[f*MM], acc);
  float a1 = g1[h] / sqrtf(v1[h] + BN_EPS);
  float c1 = b1[h] - a1*m1[h];
  ws[WS_A1 + ((size_t)(b*MM + m))*64 + h] = fmaf(a1, acc, c1);
}

// ---------------- K1b: channel norms nt[b][m], ns[b][n] ----------------
__global__ __launch_bounds__(256) void k_norms(const float* t_, const float* s_, float* ws){
  int idx = blockIdx.x*256 + threadIdx.x;
  if (idx < BB*MM){
    int b = idx >> 8, m = idx & 255;
    float acc = 0.f;
    const float* tp = t_ + (size_t)b*FF*MM + m;
    for (int f = 0; f < FF; f++){ float x = tp[f*MM]; acc = fmaf(x, x, acc); }
    ws[WS_NT + idx] = sqrtf(acc);
  } else if (idx < BB*MM + BB*NN){
    int j = idx - BB*MM;
    int b = j >> 10, n = j & 1023;
    float acc = 0.f;
    const float* sp = s_ + (size_t)b*FF*NN + n;
    for (int f = 0; f < FF; f++){ float x = sp[f*NN]; acc = fmaf(x, x, acc); }
    ws[WS_NS + j] = sqrtf(acc);
  }
}

// ---------------- K2: cosT[b][n][m] = (t.s)/max(|t||s|,eps) ----------------
__global__ __launch_bounds__(256) void k_cos(const float* t_, const float* s_, float* ws){
  __shared__ float tT[32][132];   // [m_local][f], +pad
  __shared__ float sT[64][132];   // [n_local][f]
  int t = threadIdx.x;
  int m0 = blockIdx.x*32, n0 = blockIdx.y*64, b = blockIdx.z;
  // staged as float4 (rows are 16B-aligned: MM,NN multiples of 4; m0,n0 mult of 32)
  for (int i = t; i < 32*FF/4; i += 256){
    int f = i >> 3, jm4 = i & 7;
    float4 v = *(const float4*)&t_[((size_t)(b*FF + f))*MM + m0 + jm4*4];
    tT[jm4*4+0][f] = v.x; tT[jm4*4+1][f] = v.y; tT[jm4*4+2][f] = v.z; tT[jm4*4+3][f] = v.w;
  }
  for (int i = t; i < 64*FF/4; i += 256){
    int f = i >> 4, jn4 = i & 15;
    float4 v = *(const float4*)&s_[((size_t)(b*FF + f))*NN + n0 + jn4*4];
    sT[jn4*4+0][f] = v.x; sT[jn4*4+1][f] = v.y; sT[jn4*4+2][f] = v.z; sT[jn4*4+3][f] = v.w;
  }
  __syncthreads();
  int tm = t & 7, tnn = (t >> 3) & 7, nj2 = t >> 6;
  float acc[4][2] = {{0.f,0.f},{0.f,0.f},{0.f,0.f},{0.f,0.f}};
  for (int fs = 0; fs < FF; fs += 4){
    float4 sv0 = *(const float4*)&sT[tnn + 16*nj2    ][fs];
    float4 sv1 = *(const float4*)&sT[tnn + 16*nj2 + 8][fs];
    #pragma unroll
    for (int k = 0; k < 4; k++){
      float4 tv = *(const float4*)&tT[tm + 8*k][fs];
      acc[k][0] = dot4(tv, sv0, acc[k][0]);
      acc[k][1] = dot4(tv, sv1, acc[k][1]);
    }
  }
  #pragma unroll
  for (int k = 0; k < 4; k++)
    #pragma unroll
    for (int jj = 0; jj < 2; jj++){
      int mg = m0 + tm + 8*k;
      int ng = n0 + tnn + 16*nj2 + 8*jj;
      float d = fmaxf(ws[WS_NT + b*MM + mg] * ws[WS_NS + b*NN + ng], COS_EPS);
      ws[WS_COS + ((size_t)(b*NN + ng))*MM + mg] = acc[k][jj] / d;
    }
}

// ---------------- K3: main fused m-loop ----------------
// grid (N/32, B), 256 thr. Per WG: n-tile of 32, loop all m: build h1 -> W2f gemm -> W3f gemm
// -> running max p. Epilogue: Wc1f gemm + Wc2 + bias -> out.
__global__ __launch_bounds__(256) void k_main(const float* Wc2, const float* bc2,
                                              const float* ws, float* out){
  __shared__ float W2s[64][64];   // [g][h]
  __shared__ float W3s[64][64];
  __shared__ float cosC[32][64];  // [n_local][m_chunk]
  __shared__ float h1S[32][68];   // [n_local][h], pad 68
  __shared__ float h2S[32][68];
  int t = threadIdx.x;
  int b = blockIdx.y;
  int n0 = blockIdx.x * 32;

  for (int i = t; i < 4096; i += 256){
    ((float*)W2s)[i] = ws[WS_W2F + i];
    ((float*)W3s)[i] = ws[WS_W3F + i];
  }
  int th = t & 63, tb = t >> 6;          // build mapping: h=th, n=tb*8+i
  int nq = t & 15, tg = t >> 4;          // gemm mapping: n=nq*2+jj, g=tg*4+k
  float uh = ws[WS_U + th];
  float c2r[4], c3r[4], cc1r[4];
  #pragma unroll
  for (int k = 0; k < 4; k++){
    c2r[k]  = ws[WS_C2  + tg*4 + k];
    c3r[k]  = ws[WS_C3  + tg*4 + k];
    cc1r[k] = ws[WS_CC1 + tg*4 + k];
  }
  float p[4][2] = {{0.f,0.f},{0.f,0.f},{0.f,0.f},{0.f,0.f}};
  const float* cosB = ws + WS_COS + (size_t)(b*NN + n0)*MM;
  const float* A1b  = ws + WS_A1  + (size_t)b*MM*64;
  __syncthreads();

  for (int m = 0; m < MM; m++){
    if ((m & 63) == 0){
      for (int i = t; i < 2048; i += 256){
        int n = i >> 6, mm = i & 63;
        cosC[n][mm] = cosB[(size_t)n*MM + m + mm];
      }
      __syncthreads();
    }
    // build h1 slab for this m
    float a1v = A1b[m*64 + th];
    int ml = m & 63;
    #pragma unroll
    for (int i = 0; i < 8; i++){
      int n = tb*8 + i;
      h1S[n][th] = fmaxf(fmaf(uh, cosC[n][ml], a1v), 0.f);
    }
    __syncthreads();
    // layer 2
    {
      float acc[4][2];
      #pragma unroll
      for (int k = 0; k < 4; k++){ acc[k][0] = c2r[k]; acc[k][1] = c2r[k]; }
      for (int hs = 0; hs < 64; hs += 4){
        float4 hv0 = *(const float4*)&h1S[nq*2    ][hs];
        float4 hv1 = *(const float4*)&h1S[nq*2 + 1][hs];
        #pragma unroll
        for (int k = 0; k < 4; k++){
          float4 wv = *(const float4*)&W2s[tg*4 + k][hs];
          acc[k][0] = dot4(wv, hv0, acc[k][0]);
          acc[k][1] = dot4(wv, hv1, acc[k][1]);
        }
      }
      #pragma unroll
      for (int k = 0; k < 4; k++){
        h2S[nq*2    ][tg*4 + k] = fmaxf(acc[k][0], 0.f);
        h2S[nq*2 + 1][tg*4 + k] = fmaxf(acc[k][1], 0.f);
      }
    }
    __syncthreads();
    // layer 3 + running max
    {
      float acc[4][2];
      #pragma unroll
      for (int k = 0; k < 4; k++){ acc[k][0] = c3r[k]; acc[k][1] = c3r[k]; }
      for (int hs = 0; hs < 64; hs += 4){
        float4 hv0 = *(const float4*)&h2S[nq*2    ][hs];
        float4 hv1 = *(const float4*)&h2S[nq*2 + 1][hs];
        #pragma unroll
        for (int k = 0; k < 4; k++){
          float4 wv = *(const float4*)&W3s[tg*4 + k][hs];
          acc[k][0] = dot4(wv, hv0, acc[k][0]);
          acc[k][1] = dot4(wv, hv1, acc[k][1]);
        }
      }
      #pragma unroll
      for (int k = 0; k < 4; k++){
        p[k][0] = fmaxf(p[k][0], fmaxf(acc[k][0], 0.f));
        p[k][1] = fmaxf(p[k][1], fmaxf(acc[k][1], 0.f));
      }
    }
    __syncthreads();
  }

  // epilogue: p -> LDS, c = relu(Wc1f@p + cc1), out = Wc2@c + bc2
  #pragma unroll
  for (int k = 0; k < 4; k++){
    h1S[nq*2    ][tg*4 + k] = p[k][0];
    h1S[nq*2 + 1][tg*4 + k] = p[k][1];
  }
  for (int i = t; i < 4096; i += 256) ((float*)W2s)[i] = ws[WS_WC1F + i];
  __syncthreads();
  {
    float acc[4][2];
    #pragma unroll
    for (int k = 0; k < 4; k++){ acc[k][0] = cc1r[k]; acc[k][1] = cc1r[k]; }
    for (int hs = 0; hs < 64; hs += 4){
      float4 hv0 = *(const float4*)&h1S[nq*2    ][hs];
      float4 hv1 = *(const float4*)&h1S[nq*2 + 1][hs];
      #pragma unroll
      for (int k = 0; k < 4; k++){
        float4 wv = *(const float4*)&W2s[tg*4 + k][hs];
        acc[k][0] = dot4(wv, hv0, acc[k][0]);
        acc[k][1] = dot4(wv, hv1, acc[k][1]);
      }
    }
    #pragma unroll
    for (int k = 0; k < 4; k++){
      h2S[nq*2    ][tg*4 + k] = fmaxf(acc[k][0], 0.f);
      h2S[nq*2 + 1][tg*4 + k] = fmaxf(acc[k][1], 0.f);
    }
  }
  __syncthreads();
  {
    int to = t & 127, tq = t >> 7;
    float bco = bc2[to];
    float accO[16];
    #pragma unroll
    for (int i = 0; i < 16; i++) accO[i] = bco;
    for (int h = 0; h < 64; h++){
      float w = Wc2[to*64 + h];
      #pragma unroll
      for (int i = 0; i < 16; i++) accO[i] = fmaf(w, h2S[tq*16 + i][h], accO[i]);
    }
    #pragma unroll
    for (int i = 0; i < 16; i++){
      int n = tq*16 + i;
      out[((size_t)(b*OO + to))*NN + n0 + n] = accO[i];
    }
  }
}

extern "C" void kernel_launch(void* const* d_in, const int* in_sizes, int n_in,
                              void* d_out, int out_size, void* d_ws, size_t ws_size,
                              hipStream_t stream){
  (void)in_sizes; (void)n_in; (void)out_size; (void)ws_size;
  const float* t_  = (const float*)d_in[0];
  const float* s_  = (const float*)d_in[1];
  const float* W1  = (const float*)d_in[2];
  const float* W2  = (const float*)d_in[3];
  const float* W3  = (const float*)d_in[4];
  const float* Wc1 = (const float*)d_in[5];
  const float* Wc2 = (const float*)d_in[6];
  const float* bc2 = (const float*)d_in[7];
  const float* g1 = (const float*)d_in[8],  *b1 = (const float*)d_in[9],
             * m1 = (const float*)d_in[10], *v1 = (const float*)d_in[11];
  const float* g2 = (const float*)d_in[12], *b2 = (const float*)d_in[13],
             * m2 = (const float*)d_in[14], *v2 = (const float*)d_in[15];
  const float* g3 = (const float*)d_in[16], *b3 = (const float*)d_in[17],
             * m3 = (const float*)d_in[18], *v3 = (const float*)d_in[19];
  const float* gc1 = (const float*)d_in[20], *bc1 = (const float*)d_in[21],
             * mc1 = (const float*)d_in[22], *vc1 = (const float*)d_in[23];
  float* ws = (float*)d_ws;
  float* out = (float*)d_out;

  k_fold<<<1, 256, 0, stream>>>(W1, W2, W3, Wc1,
      g1,b1,m1,v1, g2,b2,m2,v2, g3,b3,m3,v3, gc1,bc1,mc1,vc1, ws);
  k_a1<<<dim3(64, 8), 256, 0, stream>>>(t_, W1, g1, b1, m1, v1, ws);
  k_norms<<<40, 256, 0, stream>>>(t_, s_, ws);
  k_cos<<<dim3(8, 16, 8), 256, 0, stream>>>(t_, s_, ws);
  k_main<<<dim3(32, 8), 256, 0, stream>>>(Wc2, bc2, ws, out);
}

// Round 3
// 254.824 us; speedup vs baseline: 4.5275x; 4.5275x over previous
//
#include <hip/hip_runtime.h>

// P2B_XCorr: B=8, F=128, M=256, N=1024, H=64, O=128. fp32 I/O.
// R3: layers 2/3 on mfma_f32_16x16x32_bf16. h1 built in LDS [x][h] bf16 (B-operand
// layout); h2 C->B layout via per-wave LDS scratch; p = running max in C-layout regs,
// combined with int-as-float atomicMax (p>=0). Epilogue in k_tail (fp32).
// Fragment layouts (HW-verified, learn_hip m89/m120): A[m=lane&15][k=quad*8+j],
// B[k=quad*8+j][n=lane&15], D[row=quad*4+reg][col=lane&15].

#define BB 8
#define FF 128
#define MM 256
#define NN 1024
#define HH 64
#define OO 128
#define BN_EPS 1e-5f
#define COS_EPS 1e-8f

// ws layout (float offsets); total 1,726,720 floats = 6.6 MiB
#define WS_U     0
#define WS_C2    64
#define WS_C3    128
#define WS_CC1   192
#define WS_W2F   256          // [g][h] 64x64 fp32 (folded)
#define WS_W3F   4352
#define WS_WC1F  8448
#define WS_A1    12544        // [b][m][h] fp32
#define WS_NT    143616
#define WS_NS    145664
#define WS_COSB  153856       // bf16 cosT[b][m][n], 2,097,152 ushorts = 1,048,576 floats
#define WS_P     1202432      // int-as-float p[b][n][64]

typedef __attribute__((ext_vector_type(8))) short short8;
typedef __attribute__((ext_vector_type(4))) float f32x4;

__device__ __forceinline__ unsigned short f2bf(float f){
  unsigned int u = __float_as_uint(f);
  return (unsigned short)((u + 0x7FFFu + ((u >> 16) & 1u)) >> 16);
}
__device__ __forceinline__ float bf2f(unsigned short u){
  return __uint_as_float(((unsigned int)u) << 16);
}
__device__ __forceinline__ unsigned int pack2(float a, float b){
  return (unsigned int)f2bf(a) | ((unsigned int)f2bf(b) << 16);
}
__device__ __forceinline__ float dot4(float4 a, float4 b, float acc){
  acc = fmaf(a.x, b.x, acc); acc = fmaf(a.y, b.y, acc);
  acc = fmaf(a.z, b.z, acc); acc = fmaf(a.w, b.w, acc);
  return acc;
}

// ---------------- K0: fold BN params ----------------
__global__ __launch_bounds__(256) void k_fold(
    const float* W1, const float* W2, const float* W3, const float* Wc1,
    const float* g1, const float* b1, const float* m1, const float* v1,
    const float* g2, const float* b2, const float* m2, const float* v2,
    const float* g3, const float* b3, const float* m3, const float* v3,
    const float* gc1,const float* bc1,const float* mc1,const float* vc1,
    float* ws){
  int t = threadIdx.x;
  if (t < 64){
    float a1 = g1[t] / sqrtf(v1[t] + BN_EPS);
    ws[WS_U + t]   = a1 * W1[t*129];
    float a2 = g2[t] / sqrtf(v2[t] + BN_EPS);
    ws[WS_C2 + t]  = b2[t] - a2*m2[t];
    float a3 = g3[t] / sqrtf(v3[t] + BN_EPS);
    ws[WS_C3 + t]  = b3[t] - a3*m3[t];
    float ac = gc1[t] / sqrtf(vc1[t] + BN_EPS);
    ws[WS_CC1 + t] = bc1[t] - ac*mc1[t];
  }
  for (int i = t; i < 4096; i += 256){
    int g = i >> 6;
    float a2 = g2[g] / sqrtf(v2[g] + BN_EPS);
    ws[WS_W2F + i]  = a2 * W2[i];
    float a3 = g3[g] / sqrtf(v3[g] + BN_EPS);
    ws[WS_W3F + i]  = a3 * W3[i];
    float ac = gc1[g] / sqrtf(vc1[g] + BN_EPS);
    ws[WS_WC1F + i] = ac * Wc1[i];
  }
}

// ---------------- K1a: A1[b][m][h] ----------------
__global__ __launch_bounds__(256) void k_a1(const float* t_, const float* W1,
    const float* g1, const float* b1, const float* m1, const float* v1, float* ws){
  int t = threadIdx.x;
  int h = t & 63;
  int m = blockIdx.x*4 + (t >> 6);
  int b = blockIdx.y;
  float acc = 0.f;
  const float* w = W1 + h*129 + 1;
  const float* tp = t_ + (size_t)b*FF*MM + m;
  for (int f = 0; f < FF; f++) acc = fmaf(w[f], tp[f*MM], acc);
  float a1 = g1[h] / sqrtf(v1[h] + BN_EPS);
  float c1 = b1[h] - a1*m1[h];
  ws[WS_A1 + ((size_t)(b*MM + m))*64 + h] = fmaf(a1, acc, c1);
}

// ---------------- K1b: norms ----------------
__global__ __launch_bounds__(256) void k_norms(const float* t_, const float* s_, float* ws){
  int idx = blockIdx.x*256 + threadIdx.x;
  if (idx < BB*MM){
    int b = idx >> 8, m = idx & 255;
    float acc = 0.f;
    const float* tp = t_ + (size_t)b*FF*MM + m;
    for (int f = 0; f < FF; f++){ float x = tp[f*MM]; acc = fmaf(x, x, acc); }
    ws[WS_NT + idx] = sqrtf(acc);
  } else if (idx < BB*MM + BB*NN){
    int j = idx - BB*MM;
    int b = j >> 10, n = j & 1023;
    float acc = 0.f;
    const float* sp = s_ + (size_t)b*FF*NN + n;
    for (int f = 0; f < FF; f++){ float x = sp[f*NN]; acc = fmaf(x, x, acc); }
    ws[WS_NS + j] = sqrtf(acc);
  }
}

// ---------------- K2: cosT[b][m][n] (bf16, n-contig) ----------------
__global__ __launch_bounds__(256) void k_cos(const float* t_, const float* s_, float* ws){
  __shared__ float tT[32][132];
  __shared__ float sT[64][132];
  int t = threadIdx.x;
  int m0 = blockIdx.x*32, n0 = blockIdx.y*64, b = blockIdx.z;
  for (int i = t; i < 32*FF/4; i += 256){
    int f = i >> 3, jm4 = i & 7;
    float4 v = *(const float4*)&t_[((size_t)(b*FF + f))*MM + m0 + jm4*4];
    tT[jm4*4+0][f] = v.x; tT[jm4*4+1][f] = v.y; tT[jm4*4+2][f] = v.z; tT[jm4*4+3][f] = v.w;
  }
  for (int i = t; i < 64*FF/4; i += 256){
    int f = i >> 4, jn4 = i & 15;
    float4 v = *(const float4*)&s_[((size_t)(b*FF + f))*NN + n0 + jn4*4];
    sT[jn4*4+0][f] = v.x; sT[jn4*4+1][f] = v.y; sT[jn4*4+2][f] = v.z; sT[jn4*4+3][f] = v.w;
  }
  __syncthreads();
  int tnn = t & 7, tm = (t >> 3) & 7, nj2 = t >> 6;   // consecutive lanes -> consecutive n
  float acc[4][2] = {{0.f,0.f},{0.f,0.f},{0.f,0.f},{0.f,0.f}};
  for (int fs = 0; fs < FF; fs += 4){
    float4 sv0 = *(const float4*)&sT[tnn + 16*nj2    ][fs];
    float4 sv1 = *(const float4*)&sT[tnn + 16*nj2 + 8][fs];
    #pragma unroll
    for (int k = 0; k < 4; k++){
      float4 tv = *(const float4*)&tT[tm + 8*k][fs];
      acc[k][0] = dot4(tv, sv0, acc[k][0]);
      acc[k][1] = dot4(tv, sv1, acc[k][1]);
    }
  }
  unsigned short* cosw = (unsigned short*)(ws + WS_COSB);
  #pragma unroll
  for (int k = 0; k < 4; k++)
    #pragma unroll
    for (int jj = 0; jj < 2; jj++){
      int mg = m0 + tm + 8*k;
      int ng = n0 + tnn + 16*nj2 + 8*jj;
      float d = fmaxf(ws[WS_NT + b*MM + mg] * ws[WS_NS + b*NN + ng], COS_EPS);
      cosw[(size_t)(b*MM + mg)*NN + ng] = f2bf(acc[k][jj] / d);
    }
}

// ---------------- K3: main MFMA m-loop ----------------
// grid (32, 8, 2): n-tile 32, batch, m-split halves of 128. 256 thr = 4 waves.
// per m-chunk (8 m): X = 256 cols (x = m_l*32 + n_l). Wave w owns col-tiles
// (m_l in {w>>1 + 2j}, n_half = w&1). K=64 -> 2 MFMA k-steps.
__global__ __launch_bounds__(256, 2) void k_main(const float* ws, int* Pi){
  __shared__ __align__(16) unsigned short h1S[256][72];   // [x][h] bf16
  __shared__ __align__(16) unsigned short h2W[4][16][72]; // per-wave scratch [x16][g]
  __shared__ float A1S[8][64];
  __shared__ float cosS[8][32];

  int t = threadIdx.x;
  int lane = t & 63, w = t >> 6;
  int ln15 = lane & 15, quad = lane >> 4;
  int b = blockIdx.y;
  int n0 = blockIdx.x * 32;
  int m0s = blockIdx.z * 128;

  // --- weight A-frags + bias regs (one-time) ---
  const float* w2p = ws + WS_W2F;
  const float* w3p = ws + WS_W3F;
  short8 W2A[4][2], W3A[4][2];
  float c2v[4][4], c3v[4][4];
  #pragma unroll
  for (int rt = 0; rt < 4; rt++){
    int g = rt*16 + ln15;
    #pragma unroll
    for (int kk = 0; kk < 2; kk++){
      short8 a2, a3;
      #pragma unroll
      for (int j = 0; j < 8; j++){
        int k = kk*32 + quad*8 + j;
        a2[j] = (short)f2bf(w2p[g*64 + k]);
        a3[j] = (short)f2bf(w3p[g*64 + k]);
      }
      W2A[rt][kk] = a2; W3A[rt][kk] = a3;
    }
    #pragma unroll
    for (int r = 0; r < 4; r++){
      c2v[rt][r] = ws[WS_C2 + rt*16 + quad*4 + r];
      c3v[rt][r] = ws[WS_C3 + rt*16 + quad*4 + r];
    }
  }
  // build-thread params
  int h2i = lane & 31;
  int rep = (w << 1) | (lane >> 5);
  float u0 = ws[WS_U + 2*h2i], u1 = ws[WS_U + 2*h2i + 1];

  const float* A1b = ws + WS_A1 + (size_t)b*MM*64;
  const unsigned short* cosT = (const unsigned short*)(ws + WS_COSB);

  f32x4 p[4];
  #pragma unroll
  for (int rt = 0; rt < 4; rt++) p[rt] = (f32x4){0.f, 0.f, 0.f, 0.f};

  for (int mc = 0; mc < 16; mc++){
    int mbase = m0s + mc*8;
    __syncthreads();   // prev chunk's h1S/A1S/cosS reads complete
    // stage A1 chunk + cos chunk
    {
      int idx = t*2; int ml = idx >> 6, hh = idx & 63;
      *(float2*)&A1S[ml][hh] = *(const float2*)&A1b[(size_t)(mbase + ml)*64 + hh];
      int mlc = t >> 5, nl = t & 31;
      cosS[mlc][nl] = bf2f(cosT[(size_t)(b*MM + mbase + mlc)*NN + n0 + nl]);
    }
    __syncthreads();
    // build h1 slab (bf16, [x][h])
    #pragma unroll
    for (int i = 0; i < 32; i++){
      int x = i*8 + rep;
      int ml = i >> 2;
      float cv = cosS[ml][x & 31];
      float2 a12 = *(const float2*)&A1S[ml][2*h2i];
      float v0 = fmaxf(fmaf(u0, cv, a12.x), 0.f);
      float v1 = fmaxf(fmaf(u1, cv, a12.y), 0.f);
      *(unsigned int*)&h1S[x][2*h2i] = pack2(v0, v1);
    }
    __syncthreads();
    // col-tiles: layer2 MFMA -> h2 scratch -> layer3 MFMA -> running max
    #pragma unroll
    for (int j = 0; j < 4; j++){
      int mt = (w >> 1) + 2*j;
      int xb = mt*32 + (w & 1)*16;
      short8 b0 = *(const short8*)&h1S[xb + ln15][quad*8];
      short8 b1 = *(const short8*)&h1S[xb + ln15][32 + quad*8];
      f32x4 acc[4];
      #pragma unroll
      for (int rt = 0; rt < 4; rt++){
        acc[rt] = (f32x4){c2v[rt][0], c2v[rt][1], c2v[rt][2], c2v[rt][3]};
        acc[rt] = __builtin_amdgcn_mfma_f32_16x16x32_bf16(W2A[rt][0], b0, acc[rt], 0, 0, 0);
        acc[rt] = __builtin_amdgcn_mfma_f32_16x16x32_bf16(W2A[rt][1], b1, acc[rt], 0, 0, 0);
      }
      #pragma unroll
      for (int rt = 0; rt < 4; rt++){
        unsigned int lo = pack2(fmaxf(acc[rt][0], 0.f), fmaxf(acc[rt][1], 0.f));
        unsigned int hi = pack2(fmaxf(acc[rt][2], 0.f), fmaxf(acc[rt][3], 0.f));
        uint2 v; v.x = lo; v.y = hi;
        *(uint2*)&h2W[w][ln15][rt*16 + quad*4] = v;
      }
      __asm__ volatile("s_waitcnt lgkmcnt(0)" ::: "memory");
      short8 e0 = *(const short8*)&h2W[w][ln15][quad*8];
      short8 e1 = *(const short8*)&h2W[w][ln15][32 + quad*8];
      f32x4 a3[4];
      #pragma unroll
      for (int rt = 0; rt < 4; rt++){
        a3[rt] = (f32x4){c3v[rt][0], c3v[rt][1], c3v[rt][2], c3v[rt][3]};
        a3[rt] = __builtin_amdgcn_mfma_f32_16x16x32_bf16(W3A[rt][0], e0, a3[rt], 0, 0, 0);
        a3[rt] = __builtin_amdgcn_mfma_f32_16x16x32_bf16(W3A[rt][1], e1, a3[rt], 0, 0, 0);
        #pragma unroll
        for (int r = 0; r < 4; r++) p[rt][r] = fmaxf(p[rt][r], a3[rt][r]);
      }
    }
  }
  // combine partial max into global P via int-as-float atomicMax (p >= 0)
  int n = n0 + (w & 1)*16 + ln15;
  int* Pb = Pi + ((b*NN + n) << 6);
  #pragma unroll
  for (int rt = 0; rt < 4; rt++)
    #pragma unroll
    for (int r = 0; r < 4; r++)
      atomicMax(&Pb[rt*16 + quad*4 + r], __float_as_int(p[rt][r]));
}

// ---------------- K4: tail (Wc1f/relu, Wc2+bias) fp32 ----------------
__global__ __launch_bounds__(256) void k_tail(const float* Wc2, const float* bc2,
                                              const float* ws, float* out){
  __shared__ float WT[64][68];
  __shared__ float pT[32][68];
  __shared__ float cS[32][68];
  int t = threadIdx.x;
  int n0 = blockIdx.x * 32;
  int b = blockIdx.y;
  for (int i = t; i < 4096; i += 256) WT[i >> 6][i & 63] = ws[WS_WC1F + i];
  const float* Pb = ws + WS_P + ((size_t)(b*NN + n0) << 6);
  for (int i = t; i < 2048; i += 256) pT[i >> 6][i & 63] = Pb[i];
  __syncthreads();
  {
    int n = t & 31, q = t >> 5;
    for (int k = 0; k < 8; k++){
      int g = q*8 + k;
      float acc = ws[WS_CC1 + g];
      for (int hs = 0; hs < 64; hs += 4){
        float4 wv = *(const float4*)&WT[g][hs];
        float4 pv = *(const float4*)&pT[n][hs];
        acc = dot4(wv, pv, acc);
      }
      cS[n][g] = fmaxf(acc, 0.f);
    }
  }
  __syncthreads();
  {
    int o = t & 127, hf = t >> 7;
    float bco = bc2[o];
    float accO[16];
    #pragma unroll
    for (int i = 0; i < 16; i++) accO[i] = bco;
    for (int hs = 0; hs < 64; hs += 4){
      float4 w4 = *(const float4*)&Wc2[o*64 + hs];
      #pragma unroll
      for (int i = 0; i < 16; i++){
        float4 cv = *(const float4*)&cS[hf*16 + i][hs];
        accO[i] = dot4(w4, cv, accO[i]);
      }
    }
    #pragma unroll
    for (int i = 0; i < 16; i++)
      out[((size_t)(b*OO + o))*NN + n0 + hf*16 + i] = accO[i];
  }
}

extern "C" void kernel_launch(void* const* d_in, const int* in_sizes, int n_in,
                              void* d_out, int out_size, void* d_ws, size_t ws_size,
                              hipStream_t stream){
  (void)in_sizes; (void)n_in; (void)out_size; (void)ws_size;
  const float* t_  = (const float*)d_in[0];
  const float* s_  = (const float*)d_in[1];
  const float* W1  = (const float*)d_in[2];
  const float* W2  = (const float*)d_in[3];
  const float* W3  = (const float*)d_in[4];
  const float* Wc1 = (const float*)d_in[5];
  const float* Wc2 = (const float*)d_in[6];
  const float* bc2 = (const float*)d_in[7];
  const float* g1 = (const float*)d_in[8],  *b1 = (const float*)d_in[9],
             * m1 = (const float*)d_in[10], *v1 = (const float*)d_in[11];
  const float* g2 = (const float*)d_in[12], *b2 = (const float*)d_in[13],
             * m2 = (const float*)d_in[14], *v2 = (const float*)d_in[15];
  const float* g3 = (const float*)d_in[16], *b3 = (const float*)d_in[17],
             * m3 = (const float*)d_in[18], *v3 = (const float*)d_in[19];
  const float* gc1 = (const float*)d_in[20], *bc1 = (const float*)d_in[21],
             * mc1 = (const float*)d_in[22], *vc1 = (const float*)d_in[23];
  float* ws = (float*)d_ws;
  float* out = (float*)d_out;

  k_fold<<<1, 256, 0, stream>>>(W1, W2, W3, Wc1,
      g1,b1,m1,v1, g2,b2,m2,v2, g3,b3,m3,v3, gc1,bc1,mc1,vc1, ws);
  k_a1<<<dim3(64, 8), 256, 0, stream>>>(t_, W1, g1, b1, m1, v1, ws);
  k_norms<<<40, 256, 0, stream>>>(t_, s_, ws);
  k_cos<<<dim3(8, 16, 8), 256, 0, stream>>>(t_, s_, ws);
  k_main<<<dim3(32, 8, 2), 256, 0, stream>>>(ws, (int*)(ws + WS_P));
  k_tail<<<dim3(32, 8), 256, 0, stream>>>(Wc2, bc2, ws, out);
}